// Round 1
// baseline (130.737 us; speedup 1.0000x reference)
//
#include <hip/hip_runtime.h>
#include <hip/hip_bf16.h>

// Problem constants
#define B_ 4
#define S_ 4096
#define D_ 1024
#define E_ 8
#define H_ 128
#define M_ (B_*S_)   // 16384 tokens
#define K_ 1024
#define N_ 1024      // E_*H_ == D_ == 1024

typedef short bf16x8 __attribute__((ext_vector_type(8)));
typedef float f32x4 __attribute__((ext_vector_type(4)));

__device__ __forceinline__ unsigned short f2bf(float f){
  union { float f; unsigned int u; } v; v.f = f;
  unsigned int u = v.u;
  unsigned int r = (u + 0x7fffu + ((u >> 16) & 1u)) >> 16;  // RNE
  return (unsigned short)r;
}

__device__ __forceinline__ void gload16(const void* g, void* l){
  __builtin_amdgcn_global_load_lds((const __attribute__((address_space(1))) void*)g,
                                   (__attribute__((address_space(3))) void*)l, 16, 0, 0);
}

// ---------------------------------------------------------------------------
// Kernel 1: convert x (f32) -> xb (bf16) and compute gate = softmax(x.Wg + bg)
// One wave per token row.
// ---------------------------------------------------------------------------
__global__ __launch_bounds__(256)
void prep_x_gate(const float* __restrict__ x, const float* __restrict__ Wg,
                 const float* __restrict__ bg, unsigned short* __restrict__ xb,
                 float* __restrict__ gate){
  int tid = threadIdx.x;
  int lane = tid & 63;
  int m = blockIdx.x * 4 + (tid >> 6);
  const float* xr = x + (size_t)m * D_;
  unsigned short* xbr = xb + (size_t)m * D_;
  float acc[E_];
  #pragma unroll
  for (int e = 0; e < E_; ++e) acc[e] = 0.f;
  #pragma unroll
  for (int c = 0; c < D_/64; ++c){
    int d = c*64 + lane;
    float xs = xr[d];
    xbr[d] = f2bf(xs);
    const float4 w0 = *(const float4*)(Wg + (size_t)d * E_);
    const float4 w1 = *(const float4*)(Wg + (size_t)d * E_ + 4);
    acc[0] = fmaf(xs, w0.x, acc[0]); acc[1] = fmaf(xs, w0.y, acc[1]);
    acc[2] = fmaf(xs, w0.z, acc[2]); acc[3] = fmaf(xs, w0.w, acc[3]);
    acc[4] = fmaf(xs, w1.x, acc[4]); acc[5] = fmaf(xs, w1.y, acc[5]);
    acc[6] = fmaf(xs, w1.z, acc[6]); acc[7] = fmaf(xs, w1.w, acc[7]);
  }
  #pragma unroll
  for (int off = 32; off > 0; off >>= 1){
    #pragma unroll
    for (int e = 0; e < E_; ++e) acc[e] += __shfl_xor(acc[e], off, 64);
  }
  float lg[E_]; float mx = -1e30f;
  #pragma unroll
  for (int e = 0; e < E_; ++e){ lg[e] = acc[e] + bg[e]; mx = fmaxf(mx, lg[e]); }
  float s = 0.f;
  #pragma unroll
  for (int e = 0; e < E_; ++e){ lg[e] = expf(lg[e] - mx); s += lg[e]; }
  float inv = 1.f / s;
  if (lane < E_) gate[(size_t)m * E_ + lane] = lg[lane] * inv;
}

// ---------------------------------------------------------------------------
// Kernel 2: per-expert transpose+pack f32 -> bf16, n-major/k-contiguous.
// in: per-expert [R][C] row-major f32. out element (c,r) -> op[c*ostride + r].
// ---------------------------------------------------------------------------
__global__ __launch_bounds__(256)
void transpose_pack(const float* __restrict__ in, unsigned short* __restrict__ out,
                    int C, int ostride, int in_estride, int out_ebase){
  __shared__ float t[32][33];
  int e = blockIdx.z;
  const float* ip = in + (size_t)e * in_estride;
  unsigned short* op = out + (size_t)e * out_ebase;
  int tx = threadIdx.x, ty = threadIdx.y;   // 32 x 8
  int c0 = blockIdx.x * 32, r0 = blockIdx.y * 32;
  #pragma unroll
  for (int yy = 0; yy < 32; yy += 8)
    t[ty + yy][tx] = ip[(size_t)(r0 + ty + yy) * C + (c0 + tx)];
  __syncthreads();
  #pragma unroll
  for (int yy = 0; yy < 32; yy += 8)
    op[(size_t)(c0 + ty + yy) * ostride + (r0 + tx)] = f2bf(t[tx][ty + yy]);
}

// ---------------------------------------------------------------------------
// Kernel 3: 128x128-tile bf16 GEMM (m97 structure), fused MoE epilogues.
// A: [M][K] bf16 row-major.  Bt: [N][K] bf16 (n-major, k-contiguous).
// PASS 1: out = H' bf16, epilogue gate*relu(acc + b1).
// PASS 2: out = f32,     epilogue acc + sum_e gate_e*b2[e][d].
// ---------------------------------------------------------------------------
template<int PASS>
__global__ __launch_bounds__(256)
void gemm_moe(const unsigned short* __restrict__ A,
              const unsigned short* __restrict__ Bt,
              const float* __restrict__ gate,
              const float* __restrict__ bias,
              void* __restrict__ outp)
{
  __shared__ unsigned short lsA[128*32];
  __shared__ unsigned short lsB[128*32];

  // XCD-aware decode: 1024 blocks; each XCD owns a contiguous 16-row M stripe.
  int bid = blockIdx.x;
  int xcd = bid & 7, pos = bid >> 3;
  int mb = xcd * 16 + (pos >> 3);
  int nb = pos & 7;
  int m0 = mb * 128, n0 = nb * 128;

  int tid = threadIdx.x;
  int lane = tid & 63;
  int w = tid >> 6;
  int wm = w & 1, wn = w >> 1;       // 2x2 wave grid, 64x64 per wave

  f32x4 acc[4][4];
  #pragma unroll
  for (int i = 0; i < 4; ++i){
    #pragma unroll
    for (int j = 0; j < 4; ++j){ f32x4 z = {0.f,0.f,0.f,0.f}; acc[i][j] = z; }
  }

  // --- staging addresses (linear LDS dest; swizzled global source) ---
  int rr = tid >> 2;                 // row 0..63 (q adds 64)
  int sl = tid & 3;                  // 16B slot within 64B row
  int sg = sl ^ ((rr >> 1) & 3);     // global k-slot (involution)
  const unsigned short* gA  = A  + (size_t)(m0 + rr) * K_ + sg * 8;
  const unsigned short* gA2 = gA + (size_t)64 * K_;
  const unsigned short* gB  = Bt + (size_t)(n0 + rr) * K_ + sg * 8;
  const unsigned short* gB2 = gB + (size_t)64 * K_;
  unsigned short* lA  = &lsA[rr*32 + sl*8];
  unsigned short* lA2 = lA + 64*32;
  unsigned short* lB  = &lsB[rr*32 + sl*8];
  unsigned short* lB2 = lB + 64*32;

  // --- read-side fragment offsets (same XOR on the slot) ---
  int rowi = lane & 15, s = lane >> 4;
  int slot = s ^ ((rowi >> 1) & 3);
  int aoff[4], boff[4];
  #pragma unroll
  for (int i = 0; i < 4; ++i) aoff[i] = (wm*64 + i*16 + rowi)*32 + slot*8;
  #pragma unroll
  for (int j = 0; j < 4; ++j) boff[j] = (wn*64 + j*16 + rowi)*32 + slot*8;

  for (int kt = 0; kt < K_/32; ++kt){
    int ko = kt * 32;
    gload16(gA  + ko, lA);
    gload16(gA2 + ko, lA2);
    gload16(gB  + ko, lB);
    gload16(gB2 + ko, lB2);
    __syncthreads();                 // drains vmcnt, staging visible
    bf16x8 af[4], bfr[4];
    #pragma unroll
    for (int i = 0; i < 4; ++i) af[i]  = *(const bf16x8*)&lsA[aoff[i]];
    #pragma unroll
    for (int j = 0; j < 4; ++j) bfr[j] = *(const bf16x8*)&lsB[boff[j]];
    #pragma unroll
    for (int i = 0; i < 4; ++i){
      #pragma unroll
      for (int j = 0; j < 4; ++j)
        acc[i][j] = __builtin_amdgcn_mfma_f32_16x16x32_bf16(af[i], bfr[j], acc[i][j], 0, 0, 0);
    }
    __syncthreads();                 // compute done before next overwrite
  }

  if (PASS == 1){
    unsigned short* Hp = (unsigned short*)outp;
    int e = nb;                      // each n-block column IS one expert
    float b1v[4];
    #pragma unroll
    for (int j = 0; j < 4; ++j) b1v[j] = bias[e*H_ + wn*64 + j*16 + rowi];
    #pragma unroll
    for (int i = 0; i < 4; ++i){
      #pragma unroll
      for (int jj = 0; jj < 4; ++jj){
        int m = m0 + wm*64 + i*16 + s*4 + jj;
        float g = gate[(size_t)m*E_ + e];
        #pragma unroll
        for (int j = 0; j < 4; ++j){
          float v = fmaxf(acc[i][j][jj] + b1v[j], 0.f) * g;
          Hp[(size_t)m*N_ + (n0 + wn*64 + j*16 + rowi)] = f2bf(v);
        }
      }
    }
  } else {
    float* Out = (float*)outp;
    float b2v[8][4];
    #pragma unroll
    for (int j = 0; j < 4; ++j){
      int d = n0 + wn*64 + j*16 + rowi;
      #pragma unroll
      for (int e = 0; e < 8; ++e) b2v[e][j] = bias[(size_t)e*N_ + d];
    }
    #pragma unroll
    for (int i = 0; i < 4; ++i){
      #pragma unroll
      for (int jj = 0; jj < 4; ++jj){
        int m = m0 + wm*64 + i*16 + s*4 + jj;
        const float* gr = gate + (size_t)m*E_;
        float g[8];
        #pragma unroll
        for (int e = 0; e < 8; ++e) g[e] = gr[e];
        #pragma unroll
        for (int j = 0; j < 4; ++j){
          float bv = 0.f;
          #pragma unroll
          for (int e = 0; e < 8; ++e) bv = fmaf(g[e], b2v[e][j], bv);
          Out[(size_t)m*N_ + (n0 + wn*64 + j*16 + rowi)] = acc[i][j][jj] + bv;
        }
      }
    }
  }
}

// ---------------------------------------------------------------------------
extern "C" void kernel_launch(void* const* d_in, const int* in_sizes, int n_in,
                              void* d_out, int out_size, void* d_ws, size_t ws_size,
                              hipStream_t stream){
  const float* x  = (const float*)d_in[0];
  const float* W1 = (const float*)d_in[1];
  const float* b1 = (const float*)d_in[2];
  const float* W2 = (const float*)d_in[3];
  const float* b2 = (const float*)d_in[4];
  const float* Wg = (const float*)d_in[5];
  const float* bg = (const float*)d_in[6];
  float* out = (float*)d_out;

  char* ws = (char*)d_ws;
  unsigned short* xb  = (unsigned short*)(ws);                         // 32 MB bf16 x
  unsigned short* Hp  = (unsigned short*)(ws + ((size_t)32<<20));      // 32 MB bf16 H'
  unsigned short* B1T = (unsigned short*)(ws + ((size_t)64<<20));      // 2 MB
  unsigned short* B2T = (unsigned short*)(ws + ((size_t)66<<20));      // 2 MB
  float*          gate= (float*)(ws + ((size_t)68<<20));               // 512 KB

  // x -> bf16 + gate softmax
  hipLaunchKernelGGL(prep_x_gate, dim3(M_/4), dim3(256), 0, stream, x, Wg, bg, xb, gate);
  // W1 [E][D][H] -> B1T[(e*128+h)][d]
  hipLaunchKernelGGL(transpose_pack, dim3(128/32, 1024/32, 8), dim3(32,8), 0, stream,
                     W1, B1T, 128, 1024, 1024*128, 128*1024);
  // W2 [E][H][D] -> B2T[d][(e*128+h)]
  hipLaunchKernelGGL(transpose_pack, dim3(1024/32, 128/32, 8), dim3(32,8), 0, stream,
                     W2, B2T, 1024, 1024, 128*1024, 128);
  // Pass 1: H' = gate * relu(x.W1 + b1)
  hipLaunchKernelGGL((gemm_moe<1>), dim3(1024), dim3(256), 0, stream,
                     xb, B1T, gate, b1, (void*)Hp);
  // Pass 2: out = H'.W2 + gate.b2
  hipLaunchKernelGGL((gemm_moe<2>), dim3(1024), dim3(256), 0, stream,
                     Hp, B2T, gate, b2, (void*)out);
}

// Round 3
// 106.340 us; speedup vs baseline: 1.2294x; 1.2294x over previous
//
#include <hip/hip_runtime.h>
#include <hip/hip_bf16.h>

// Problem constants
#define B_ 4
#define S_ 4096
#define D_ 1024
#define E_ 8
#define H_ 128
#define M_ (B_*S_)   // 16384 tokens
#define K_ 1024
#define N_ 1024      // E_*H_ == D_ == 1024
#define NT_ (K_/64)  // 16 K-tiles of BK=64
#define NIT_ (NT_/2) // 8 iterations, 2 K-tiles each

typedef short bf16x8 __attribute__((ext_vector_type(8)));
typedef float f32x4 __attribute__((ext_vector_type(4)));

__device__ __forceinline__ unsigned short f2bf(float f){
  union { float f; unsigned int u; } v; v.f = f;
  unsigned int u = v.u;
  unsigned int r = (u + 0x7fffu + ((u >> 16) & 1u)) >> 16;  // RNE
  return (unsigned short)r;
}

__device__ __forceinline__ void gload16(const void* g, void* l){
  __builtin_amdgcn_global_load_lds((const __attribute__((address_space(1))) void*)g,
                                   (__attribute__((address_space(3))) void*)l, 16, 0, 0);
}

// ---------------------------------------------------------------------------
// Kernel 1: x (f32) -> xb (bf16) and gate = softmax(x.Wg + bg). 1 wave/token.
// ---------------------------------------------------------------------------
__global__ __launch_bounds__(256)
void prep_x_gate(const float* __restrict__ x, const float* __restrict__ Wg,
                 const float* __restrict__ bg, unsigned short* __restrict__ xb,
                 float* __restrict__ gate){
  int tid = threadIdx.x;
  int lane = tid & 63;
  int m = blockIdx.x * 4 + (tid >> 6);
  const float* xr = x + (size_t)m * D_;
  unsigned short* xbr = xb + (size_t)m * D_;
  float acc[E_];
  #pragma unroll
  for (int e = 0; e < E_; ++e) acc[e] = 0.f;
  #pragma unroll
  for (int c = 0; c < D_/64; ++c){
    int d = c*64 + lane;
    float xs = xr[d];
    xbr[d] = f2bf(xs);
    const float4 w0 = *(const float4*)(Wg + (size_t)d * E_);
    const float4 w1 = *(const float4*)(Wg + (size_t)d * E_ + 4);
    acc[0] = fmaf(xs, w0.x, acc[0]); acc[1] = fmaf(xs, w0.y, acc[1]);
    acc[2] = fmaf(xs, w0.z, acc[2]); acc[3] = fmaf(xs, w0.w, acc[3]);
    acc[4] = fmaf(xs, w1.x, acc[4]); acc[5] = fmaf(xs, w1.y, acc[5]);
    acc[6] = fmaf(xs, w1.z, acc[6]); acc[7] = fmaf(xs, w1.w, acc[7]);
  }
  #pragma unroll
  for (int off = 32; off > 0; off >>= 1){
    #pragma unroll
    for (int e = 0; e < E_; ++e) acc[e] += __shfl_xor(acc[e], off, 64);
  }
  float lg[E_]; float mx = -1e30f;
  #pragma unroll
  for (int e = 0; e < E_; ++e){ lg[e] = acc[e] + bg[e]; mx = fmaxf(mx, lg[e]); }
  float s = 0.f;
  #pragma unroll
  for (int e = 0; e < E_; ++e){ lg[e] = expf(lg[e] - mx); s += lg[e]; }
  float inv = 1.f / s;
  if (lane < E_) gate[(size_t)m * E_ + lane] = lg[lane] * inv;
}

// ---------------------------------------------------------------------------
// Kernel 2: per-expert transpose+pack f32 -> bf16, n-major/k-contiguous.
// ---------------------------------------------------------------------------
__global__ __launch_bounds__(256)
void transpose_pack(const float* __restrict__ in, unsigned short* __restrict__ out,
                    int C, int ostride, int in_estride, int out_ebase){
  __shared__ float t[32][33];
  int e = blockIdx.z;
  const float* ip = in + (size_t)e * in_estride;
  unsigned short* op = out + (size_t)e * out_ebase;
  int tx = threadIdx.x, ty = threadIdx.y;   // 32 x 8
  int c0 = blockIdx.x * 32, r0 = blockIdx.y * 32;
  #pragma unroll
  for (int yy = 0; yy < 32; yy += 8)
    t[ty + yy][tx] = ip[(size_t)(r0 + ty + yy) * C + (c0 + tx)];
  __syncthreads();
  #pragma unroll
  for (int yy = 0; yy < 32; yy += 8)
    op[(size_t)(c0 + ty + yy) * ostride + (r0 + tx)] = f2bf(t[tx][ty + yy]);
}

// ---------------------------------------------------------------------------
// Kernel 3: 256x256-tile, BK=64, 8-wave, 8-phase (T2+T3+T4+T5) bf16 GEMM.
// A: [M][K] bf16 row-major.  Bt: [N][K] bf16 (n-major, k-contiguous).
// LDS (128 KiB): A[buf][half][128][64] at 0, B same at +32768 shorts.
// Swizzle: 16B slot ^= (row&7) applied on the global SOURCE (stage) and the
// ds_read address (same involution both sides).
// Schedule (iteration i computes tiles 2i (buf0), 2i+1 (buf1)):
//   stages: P1: (2i+1).Ah1->b1  P3: (2i+2).Bh0->b0  P4: (2i+2).Bh1->b0
//           P5: (2i+2).Ah0->b0  P6: (2i+2).Ah1->b0  P7: (2i+3).Bh0->b1
//           P8: (2i+3).Bh1->b1, (2i+3).Ah0->b1
//   every stage issues strictly after its half-buffer's last reader phase;
//   waits: vmcnt(4) end-P4 (vmcnt(0) on the FINAL iteration: without P3/P4's
//   +4 loads, vmcnt(4) would leave the last tile's A halves in flight — race),
//   vmcnt(6) end-P8. Counted, never 0 mid-loop.
// PASS 1: out = H' bf16, epilogue gate*relu(acc + b1).
// PASS 2: out = f32,     epilogue acc + sum_e gate_e*b2[e][d].
// ---------------------------------------------------------------------------
template<int PASS>
__global__ __launch_bounds__(512, 2)
void gemm_moe8(const unsigned short* __restrict__ A,
               const unsigned short* __restrict__ Bt,
               const float* __restrict__ gate,
               const float* __restrict__ bias,
               void* __restrict__ outp)
{
  __shared__ unsigned short lds[65536];   // 128 KiB

  // XCD-aware decode: 256 blocks, each XCD owns an 8-mb stripe x all 4 nb.
  int bid = blockIdx.x;
  int xcd = bid & 7, pos = bid >> 3;
  int mb = xcd * 8 + (pos >> 2);
  int nb = pos & 3;
  int m0 = mb * 256, n0 = nb * 256;

  int tid = threadIdx.x;
  int lane = tid & 63;
  int w = tid >> 6;
  int wm = w & 1, wn = w >> 1;            // 2x4 wave grid; wave owns 128x64
  int rowi = lane & 15, s4 = lane >> 4;

  // --- staging addresses (linear LDS dest; swizzled global source) ---
  int sg = (tid & 7) ^ ((tid >> 3) & 7);
  const unsigned short* gA = A  + (size_t)(m0 + (tid >> 3)) * K_ + sg * 8;
  const unsigned short* gB = Bt + (size_t)(n0 + (tid >> 3)) * K_ + sg * 8;
  int t8 = tid * 8;

#define STAGE_A(b,h,kt) do{ const unsigned short* g_ = gA + (size_t)((h)*128)*K_ + (kt)*64; \
  gload16(g_,                 &lds[(b)*16384 + (h)*8192 + t8]); \
  gload16(g_ + (size_t)64*K_, &lds[(b)*16384 + (h)*8192 + t8 + 4096]); }while(0)
#define STAGE_B(b,h,kt) do{ const unsigned short* g_ = gB + (size_t)((h)*128)*K_ + (kt)*64; \
  gload16(g_,                 &lds[32768 + (b)*16384 + (h)*8192 + t8]); \
  gload16(g_ + (size_t)64*K_, &lds[32768 + (b)*16384 + (h)*8192 + t8 + 4096]); }while(0)

  // --- read-side fragment offsets (same XOR on the slot) ---
  int bk0 = rowi*64 + (( s4     ) ^ (rowi & 7)) * 8;
  int bk1 = rowi*64 + ((4 + s4  ) ^ (rowi & 7)) * 8;
  int abase0 = wm * 8192;
  int bbase0 = 32768 + (wn >> 1) * 8192 + (wn & 1) * 4096;

  f32x4 acc[8][4];
  #pragma unroll
  for (int i = 0; i < 8; ++i){
    #pragma unroll
    for (int j = 0; j < 4; ++j){ f32x4 z = {0.f,0.f,0.f,0.f}; acc[i][j] = z; }
  }
  bf16x8 af[4][2], bfr[4][2];

#define READ_A(b,r) do{ int ab_ = (b)*16384 + abase0; \
  _Pragma("unroll") for (int f2 = 0; f2 < 4; ++f2){ \
    af[f2][0] = *(const bf16x8*)&lds[ab_ + ((r)*4+f2)*1024 + bk0]; \
    af[f2][1] = *(const bf16x8*)&lds[ab_ + ((r)*4+f2)*1024 + bk1]; } }while(0)
#define READ_B(b,c) do{ int bb_ = (b)*16384 + bbase0; \
  _Pragma("unroll") for (int j2 = 0; j2 < 2; ++j2){ \
    bfr[(c)*2+j2][0] = *(const bf16x8*)&lds[bb_ + ((c)*2+j2)*1024 + bk0]; \
    bfr[(c)*2+j2][1] = *(const bf16x8*)&lds[bb_ + ((c)*2+j2)*1024 + bk1]; } }while(0)
#define MFMA16(r,c) do{ \
  _Pragma("unroll") for (int f2 = 0; f2 < 4; ++f2) \
  _Pragma("unroll") for (int j2 = 0; j2 < 2; ++j2){ \
    acc[(r)*4+f2][(c)*2+j2] = __builtin_amdgcn_mfma_f32_16x16x32_bf16(af[f2][0], bfr[(c)*2+j2][0], acc[(r)*4+f2][(c)*2+j2], 0,0,0); \
    acc[(r)*4+f2][(c)*2+j2] = __builtin_amdgcn_mfma_f32_16x16x32_bf16(af[f2][1], bfr[(c)*2+j2][1], acc[(r)*4+f2][(c)*2+j2], 0,0,0); \
  } }while(0)

#define PH_MID  __builtin_amdgcn_s_barrier(); \
                asm volatile("s_waitcnt lgkmcnt(0)" ::: "memory"); \
                __builtin_amdgcn_s_setprio(1)
#define PH_END  __builtin_amdgcn_s_setprio(0); __builtin_amdgcn_s_barrier()
#define PH_END_VM(N) __builtin_amdgcn_s_setprio(0); \
                asm volatile("s_waitcnt vmcnt(" #N ")" ::: "memory"); \
                __builtin_amdgcn_s_barrier()

  // prologue: tile0 -> buf0 (all 4 halves); tile1 -> buf1 (Bh0,Bh1,Ah0)
  STAGE_B(0,0,0); STAGE_B(0,1,0);
  STAGE_A(0,0,0); STAGE_A(0,1,0);
  STAGE_B(1,0,1); STAGE_B(1,1,1);
  STAGE_A(1,0,1);
  asm volatile("s_waitcnt vmcnt(0)" ::: "memory");
  __builtin_amdgcn_s_barrier();

  #pragma unroll 1
  for (int it = 0; it < NIT_; ++it){
    int kt1  = 2*it + 1;
    int ktn0 = 2*it + 2, ktn1 = 2*it + 3;
    bool more = (it < NIT_ - 1);
    // P1 — tile 2i quadrant (0,0)
    READ_A(0,0); READ_B(0,0);
    STAGE_A(1,1,kt1);
    PH_MID; MFMA16(0,0); PH_END;
    // P2 — quadrant (0,1)
    READ_B(0,1);
    PH_MID; MFMA16(0,1); PH_END;
    // P3 — quadrant (1,1)
    READ_A(0,1);
    if (more) STAGE_B(0,0,ktn0);
    PH_MID; MFMA16(1,1); PH_END;
    // P4 — quadrant (1,0)
    if (more) STAGE_B(0,1,ktn0);
    PH_MID; MFMA16(1,0);
    __builtin_amdgcn_s_setprio(0);
    if (more) { asm volatile("s_waitcnt vmcnt(4)" ::: "memory"); }
    else      { asm volatile("s_waitcnt vmcnt(0)" ::: "memory"); }   // final tile's A halves
    __builtin_amdgcn_s_barrier();
    // P5 — tile 2i+1 quadrant (0,0)
    READ_A(1,0); READ_B(1,0);
    if (more) STAGE_A(0,0,ktn0);
    PH_MID; MFMA16(0,0); PH_END;
    // P6 — quadrant (0,1)
    READ_B(1,1);
    if (more) STAGE_A(0,1,ktn0);
    PH_MID; MFMA16(0,1); PH_END;
    // P7 — quadrant (1,1)
    READ_A(1,1);
    if (more) STAGE_B(1,0,ktn1);
    PH_MID; MFMA16(1,1); PH_END;
    // P8 — quadrant (1,0)
    if (more){ STAGE_B(1,1,ktn1); STAGE_A(1,0,ktn1); }
    PH_MID; MFMA16(1,0); PH_END_VM(6);
  }

  // ----------------------- epilogue -----------------------
  if (PASS == 1){
    unsigned short* Hp = (unsigned short*)outp;
    int e = nb*2 + (wn >> 1);              // 64-col wave range sits in one expert
    int ncol0 = n0 + wn*64;
    float b1v[4];
    #pragma unroll
    for (int j = 0; j < 4; ++j) b1v[j] = bias[e*H_ + (wn&1)*64 + j*16 + rowi];
    #pragma unroll
    for (int fi = 0; fi < 8; ++fi){
      #pragma unroll
      for (int jj = 0; jj < 4; ++jj){
        int m = m0 + wm*128 + fi*16 + s4*4 + jj;
        float g = gate[(size_t)m*E_ + e];
        #pragma unroll
        for (int j = 0; j < 4; ++j){
          float v = fmaxf(acc[fi][j][jj] + b1v[j], 0.f) * g;
          Hp[(size_t)m*N_ + ncol0 + j*16 + rowi] = f2bf(v);
        }
      }
    }
  } else {
    float* Out = (float*)outp;
    int ncol0 = n0 + wn*64;
    float b2v[8][4];
    #pragma unroll
    for (int j = 0; j < 4; ++j){
      int n = ncol0 + j*16 + rowi;
      #pragma unroll
      for (int e = 0; e < 8; ++e) b2v[e][j] = bias[(size_t)e*N_ + n];
    }
    #pragma unroll
    for (int fi = 0; fi < 8; ++fi){
      #pragma unroll
      for (int jj = 0; jj < 4; ++jj){
        int m = m0 + wm*128 + fi*16 + s4*4 + jj;
        const float* gr = gate + (size_t)m*E_;
        float bv[4] = {0.f,0.f,0.f,0.f};
        #pragma unroll
        for (int e = 0; e < 8; ++e){
          float g = gr[e];
          #pragma unroll
          for (int j = 0; j < 4; ++j) bv[j] = fmaf(g, b2v[e][j], bv[j]);
        }
        #pragma unroll
        for (int j = 0; j < 4; ++j)
          Out[(size_t)m*N_ + ncol0 + j*16 + rowi] = acc[fi][j][jj] + bv[j];
      }
    }
  }
#undef STAGE_A
#undef STAGE_B
#undef READ_A
#undef READ_B
#undef MFMA16
#undef PH_MID
#undef PH_END
#undef PH_END_VM
}

// ---------------------------------------------------------------------------
extern "C" void kernel_launch(void* const* d_in, const int* in_sizes, int n_in,
                              void* d_out, int out_size, void* d_ws, size_t ws_size,
                              hipStream_t stream){
  const float* x  = (const float*)d_in[0];
  const float* W1 = (const float*)d_in[1];
  const float* b1 = (const float*)d_in[2];
  const float* W2 = (const float*)d_in[3];
  const float* b2 = (const float*)d_in[4];
  const float* Wg = (const float*)d_in[5];
  const float* bg = (const float*)d_in[6];
  float* out = (float*)d_out;

  char* ws = (char*)d_ws;
  unsigned short* xb  = (unsigned short*)(ws);                         // 32 MB bf16 x
  unsigned short* Hp  = (unsigned short*)(ws + ((size_t)32<<20));      // 32 MB bf16 H'
  unsigned short* B1T = (unsigned short*)(ws + ((size_t)64<<20));      // 2 MB
  unsigned short* B2T = (unsigned short*)(ws + ((size_t)66<<20));      // 2 MB
  float*          gate= (float*)(ws + ((size_t)68<<20));               // 512 KB

  hipLaunchKernelGGL(prep_x_gate, dim3(M_/4), dim3(256), 0, stream, x, Wg, bg, xb, gate);
  hipLaunchKernelGGL(transpose_pack, dim3(128/32, 1024/32, 8), dim3(32,8), 0, stream,
                     W1, B1T, 128, 1024, 1024*128, 128*1024);
  hipLaunchKernelGGL(transpose_pack, dim3(1024/32, 128/32, 8), dim3(32,8), 0, stream,
                     W2, B2T, 1024, 1024, 128*1024, 128);
  hipLaunchKernelGGL((gemm_moe8<1>), dim3(256), dim3(512), 0, stream,
                     xb, B1T, gate, b1, (void*)Hp);
  hipLaunchKernelGGL((gemm_moe8<2>), dim3(256), dim3(512), 0, stream,
                     Hp, B2T, gate, b2, (void*)out);
}